// Round 1
// baseline (81.829 us; speedup 1.0000x reference)
//
#include <hip/hip_runtime.h>
#include <hip/hip_bf16.h>

#define N_POINTS 16384
#define N_GAUSS  3200
#define N_CLASSES 14
#define PARAM_STRIDE 24   // floats per gaussian in packed params

// ---------------------------------------------------------------------------
// Kernel 1: pack per-gaussian parameters.
// layout per gaussian (24 floats):
//  [0..5]  s00,s11,s22,s01,s02,s12   (= k*A diag, 2k*A offdiag; k = -log2(e)/2)
//  [6..8]  mean x,y,z
//  [9]     log2(opacity)
//  [10..23] semantics[14]
// ---------------------------------------------------------------------------
__global__ void gauss_prep_kernel(const float* __restrict__ means,
                                  const float* __restrict__ scales,
                                  const float* __restrict__ rotations,
                                  const float* __restrict__ opacities,
                                  const float* __restrict__ semantics,
                                  float* __restrict__ params) {
    int g = blockIdx.x * blockDim.x + threadIdx.x;
    if (g >= N_GAUSS) return;

    float qw = rotations[g * 4 + 0];
    float qx = rotations[g * 4 + 1];
    float qy = rotations[g * 4 + 2];
    float qz = rotations[g * 4 + 3];
    float inv = 1.0f / sqrtf(qw * qw + qx * qx + qy * qy + qz * qz);
    qw *= inv; qx *= inv; qy *= inv; qz *= inv;

    // rows of R (row-major, matches reference stack order)
    float r00 = 1.0f - 2.0f * (qy * qy + qz * qz);
    float r01 = 2.0f * (qx * qy - qw * qz);
    float r02 = 2.0f * (qx * qz + qw * qy);
    float r10 = 2.0f * (qx * qy + qw * qz);
    float r11 = 1.0f - 2.0f * (qx * qx + qz * qz);
    float r12 = 2.0f * (qy * qz - qw * qx);
    float r20 = 2.0f * (qx * qz - qw * qy);
    float r21 = 2.0f * (qy * qz + qw * qx);
    float r22 = 1.0f - 2.0f * (qx * qx + qy * qy);

    float sx = scales[g * 3 + 0];
    float sy = scales[g * 3 + 1];
    float sz = scales[g * 3 + 2];
    float iv0 = 1.0f / (sx * sx);
    float iv1 = 1.0f / (sy * sy);
    float iv2 = 1.0f / (sz * sz);

    // A = R^T D R  (einsum 'gki,gk,gkj->gij')
    float a00 = iv0 * r00 * r00 + iv1 * r10 * r10 + iv2 * r20 * r20;
    float a01 = iv0 * r00 * r01 + iv1 * r10 * r11 + iv2 * r20 * r21;
    float a02 = iv0 * r00 * r02 + iv1 * r10 * r12 + iv2 * r20 * r22;
    float a11 = iv0 * r01 * r01 + iv1 * r11 * r11 + iv2 * r21 * r21;
    float a12 = iv0 * r01 * r02 + iv1 * r11 * r12 + iv2 * r21 * r22;
    float a22 = iv0 * r02 * r02 + iv1 * r12 * r12 + iv2 * r22 * r22;

    const float k = -0.72134752044448170368f;  // -0.5 * log2(e)

    float* p = params + g * PARAM_STRIDE;
    p[0] = k * a00;
    p[1] = k * a11;
    p[2] = k * a22;
    p[3] = 2.0f * k * a01;
    p[4] = 2.0f * k * a02;
    p[5] = 2.0f * k * a12;
    p[6] = means[g * 3 + 0];
    p[7] = means[g * 3 + 1];
    p[8] = means[g * 3 + 2];
    p[9] = log2f(opacities[g]);
#pragma unroll
    for (int c = 0; c < N_CLASSES; ++c)
        p[10 + c] = semantics[g * N_CLASSES + c];
}

// ---------------------------------------------------------------------------
// Kernel 2: main evaluation.
// Block = 512 threads = 8 waves. Each wave: 64 lanes = 64 points (shared by
// all 8 waves), wave id selects a 400-gaussian chunk. Gaussian params are
// wave-uniform per iteration -> scalar loads. LDS reduce across the 8 waves,
// then one coalesced store. No atomics; every output written exactly once.
// ---------------------------------------------------------------------------
__launch_bounds__(512)
__global__ void gauss_occ_main_kernel(const float* __restrict__ xyz,
                                      const float* __restrict__ params,
                                      float* __restrict__ out) {
    __shared__ float red[8][64][N_CLASSES];   // 28 KiB

    const int lane = threadIdx.x & 63;
    const int wid  = __builtin_amdgcn_readfirstlane((int)(threadIdx.x >> 6));
    const int pt   = blockIdx.x * 64 + lane;

    const float px = xyz[pt * 3 + 0];
    const float py = xyz[pt * 3 + 1];
    const float pz = xyz[pt * 3 + 2];

    float acc[N_CLASSES];
#pragma unroll
    for (int c = 0; c < N_CLASSES; ++c) acc[c] = 0.0f;

    const int gPerWave = N_GAUSS / 8;          // 400
    const int g0 = wid * gPerWave;
    const int g1 = g0 + gPerWave;

#pragma unroll 2
    for (int g = g0; g < g1; ++g) {
        const float* gp = params + g * PARAM_STRIDE;  // wave-uniform -> s_load
        const float s00 = gp[0], s11 = gp[1], s22 = gp[2];
        const float s01 = gp[3], s02 = gp[4], s12 = gp[5];
        const float dx = px - gp[6];
        const float dy = py - gp[7];
        const float dz = pz - gp[8];

        float t0 = fmaf(s02, dz, fmaf(s01, dy, s00 * dx));
        float t1 = fmaf(s12, dz, s11 * dy);
        float t2 = s22 * dz;
        float arg = fmaf(dx, t0, fmaf(dy, t1, fmaf(dz, t2, gp[9])));
        float w = __builtin_amdgcn_exp2f(arg);   // = opacity * exp(-0.5*q)

#pragma unroll
        for (int c = 0; c < N_CLASSES; ++c)
            acc[c] = fmaf(w, gp[10 + c], acc[c]);
    }

#pragma unroll
    for (int c = 0; c < N_CLASSES; ++c) red[wid][lane][c] = acc[c];
    __syncthreads();

    for (int idx = threadIdx.x; idx < 64 * N_CLASSES; idx += 512) {
        const int l = idx / N_CLASSES;
        const int c = idx - l * N_CLASSES;
        float s = 0.0f;
#pragma unroll
        for (int wq = 0; wq < 8; ++wq) s += red[wq][l][c];
        out[(blockIdx.x * 64 + l) * N_CLASSES + c] = s;
    }
}

extern "C" void kernel_launch(void* const* d_in, const int* in_sizes, int n_in,
                              void* d_out, int out_size, void* d_ws, size_t ws_size,
                              hipStream_t stream) {
    const float* xyz       = (const float*)d_in[0];
    const float* means     = (const float*)d_in[1];
    const float* scales    = (const float*)d_in[2];
    const float* rotations = (const float*)d_in[3];
    const float* opacities = (const float*)d_in[4];
    const float* semantics = (const float*)d_in[5];
    float* out = (float*)d_out;
    float* params = (float*)d_ws;   // needs N_GAUSS*24*4 = 307,200 bytes

    hipLaunchKernelGGL(gauss_prep_kernel,
                       dim3((N_GAUSS + 255) / 256), dim3(256), 0, stream,
                       means, scales, rotations, opacities, semantics, params);

    hipLaunchKernelGGL(gauss_occ_main_kernel,
                       dim3(N_POINTS / 64), dim3(512), 0, stream,
                       xyz, params, out);
}

// Round 2
// 45.889 us; speedup vs baseline: 1.7832x; 1.7832x over previous
//
#include <hip/hip_runtime.h>
#include <hip/hip_bf16.h>

#define N_POINTS 16384
#define N_GAUSS  3200
#define N_CLASSES 14
#define PARAM_STRIDE 24   // floats per gaussian in packed params
#define N_SPLIT 4         // gaussian-dimension splits across blocks

// ---------------------------------------------------------------------------
// Kernel 1: pack per-gaussian parameters.
// layout per gaussian (24 floats):
//  [0..5]  s00,s11,s22,s01,s02,s12   (= k*A diag, 2k*A offdiag; k = -log2(e)/2)
//  [6..8]  mean x,y,z
//  [9]     log2(opacity)
//  [10..23] semantics[14]
// ---------------------------------------------------------------------------
__global__ void gauss_prep_kernel(const float* __restrict__ means,
                                  const float* __restrict__ scales,
                                  const float* __restrict__ rotations,
                                  const float* __restrict__ opacities,
                                  const float* __restrict__ semantics,
                                  float* __restrict__ params) {
    int g = blockIdx.x * blockDim.x + threadIdx.x;
    if (g >= N_GAUSS) return;

    float qw = rotations[g * 4 + 0];
    float qx = rotations[g * 4 + 1];
    float qy = rotations[g * 4 + 2];
    float qz = rotations[g * 4 + 3];
    float inv = 1.0f / sqrtf(qw * qw + qx * qx + qy * qy + qz * qz);
    qw *= inv; qx *= inv; qy *= inv; qz *= inv;

    float r00 = 1.0f - 2.0f * (qy * qy + qz * qz);
    float r01 = 2.0f * (qx * qy - qw * qz);
    float r02 = 2.0f * (qx * qz + qw * qy);
    float r10 = 2.0f * (qx * qy + qw * qz);
    float r11 = 1.0f - 2.0f * (qx * qx + qz * qz);
    float r12 = 2.0f * (qy * qz - qw * qx);
    float r20 = 2.0f * (qx * qz - qw * qy);
    float r21 = 2.0f * (qy * qz + qw * qx);
    float r22 = 1.0f - 2.0f * (qx * qx + qy * qy);

    float sx = scales[g * 3 + 0];
    float sy = scales[g * 3 + 1];
    float sz = scales[g * 3 + 2];
    float iv0 = 1.0f / (sx * sx);
    float iv1 = 1.0f / (sy * sy);
    float iv2 = 1.0f / (sz * sz);

    // A = R^T D R  (einsum 'gki,gk,gkj->gij')
    float a00 = iv0 * r00 * r00 + iv1 * r10 * r10 + iv2 * r20 * r20;
    float a01 = iv0 * r00 * r01 + iv1 * r10 * r11 + iv2 * r20 * r21;
    float a02 = iv0 * r00 * r02 + iv1 * r10 * r12 + iv2 * r20 * r22;
    float a11 = iv0 * r01 * r01 + iv1 * r11 * r11 + iv2 * r21 * r21;
    float a12 = iv0 * r01 * r02 + iv1 * r11 * r12 + iv2 * r21 * r22;
    float a22 = iv0 * r02 * r02 + iv1 * r12 * r12 + iv2 * r22 * r22;

    const float k = -0.72134752044448170368f;  // -0.5 * log2(e)

    float* p = params + g * PARAM_STRIDE;
    p[0] = k * a00;
    p[1] = k * a11;
    p[2] = k * a22;
    p[3] = 2.0f * k * a01;
    p[4] = 2.0f * k * a02;
    p[5] = 2.0f * k * a12;
    p[6] = means[g * 3 + 0];
    p[7] = means[g * 3 + 1];
    p[8] = means[g * 3 + 2];
    p[9] = log2f(opacities[g]);
#pragma unroll
    for (int c = 0; c < N_CLASSES; ++c)
        p[10 + c] = semantics[g * N_CLASSES + c];
}

// ---------------------------------------------------------------------------
// Kernel 2: main evaluation.
// Grid = 256 point-groups x N_SPLIT gaussian-splits = 1024 blocks
// (4 blocks/CU -> 32 waves/CU = full wave slots; was 1 block/CU before).
// Block = 512 threads = 8 waves; lane = point, wave+split selects a
// 100-gaussian chunk (wave-uniform -> scalar loads). LDS-reduce the 8 waves,
// then one fp32 HW atomic per output element per split (d_out pre-zeroed).
// ---------------------------------------------------------------------------
__launch_bounds__(512)
__global__ void gauss_occ_main_kernel(const float* __restrict__ xyz,
                                      const float* __restrict__ params,
                                      float* __restrict__ out) {
    __shared__ float red[8][64][N_CLASSES];   // 28 KiB

    const int lane  = threadIdx.x & 63;
    const int wid   = __builtin_amdgcn_readfirstlane((int)(threadIdx.x >> 6));
    const int group = blockIdx.x >> 2;            // 0..255  (point group)
    const int split = blockIdx.x & (N_SPLIT - 1); // 0..3    (gaussian split)
    const int pt    = group * 64 + lane;

    const float px = xyz[pt * 3 + 0];
    const float py = xyz[pt * 3 + 1];
    const float pz = xyz[pt * 3 + 2];

    float acc[N_CLASSES];
#pragma unroll
    for (int c = 0; c < N_CLASSES; ++c) acc[c] = 0.0f;

    const int gPerChunk = N_GAUSS / (N_SPLIT * 8);     // 100
    const int chunk = split * 8 + wid;                 // 0..31
    const int g0 = chunk * gPerChunk;
    const int g1 = g0 + gPerChunk;

#pragma unroll 2
    for (int g = g0; g < g1; ++g) {
        const float* gp = params + g * PARAM_STRIDE;  // wave-uniform -> s_load
        const float s00 = gp[0], s11 = gp[1], s22 = gp[2];
        const float s01 = gp[3], s02 = gp[4], s12 = gp[5];
        const float dx = px - gp[6];
        const float dy = py - gp[7];
        const float dz = pz - gp[8];

        float t0 = fmaf(s02, dz, fmaf(s01, dy, s00 * dx));
        float t1 = fmaf(s12, dz, s11 * dy);
        float t2 = s22 * dz;
        float arg = fmaf(dx, t0, fmaf(dy, t1, fmaf(dz, t2, gp[9])));
        float w = __builtin_amdgcn_exp2f(arg);   // = opacity * exp(-0.5*q)

#pragma unroll
        for (int c = 0; c < N_CLASSES; ++c)
            acc[c] = fmaf(w, gp[10 + c], acc[c]);
    }

#pragma unroll
    for (int c = 0; c < N_CLASSES; ++c) red[wid][lane][c] = acc[c];
    __syncthreads();

    for (int idx = threadIdx.x; idx < 64 * N_CLASSES; idx += 512) {
        const int l = idx / N_CLASSES;
        const int c = idx - l * N_CLASSES;
        float s = 0.0f;
#pragma unroll
        for (int wq = 0; wq < 8; ++wq) s += red[wq][l][c];
        unsafeAtomicAdd(&out[(group * 64 + l) * N_CLASSES + c], s);
    }
}

extern "C" void kernel_launch(void* const* d_in, const int* in_sizes, int n_in,
                              void* d_out, int out_size, void* d_ws, size_t ws_size,
                              hipStream_t stream) {
    const float* xyz       = (const float*)d_in[0];
    const float* means     = (const float*)d_in[1];
    const float* scales    = (const float*)d_in[2];
    const float* rotations = (const float*)d_in[3];
    const float* opacities = (const float*)d_in[4];
    const float* semantics = (const float*)d_in[5];
    float* out = (float*)d_out;
    float* params = (float*)d_ws;   // needs N_GAUSS*24*4 = 307,200 bytes

    // d_out accumulated via atomics -> zero it every call (deterministic).
    hipMemsetAsync(d_out, 0, (size_t)out_size * sizeof(float), stream);

    hipLaunchKernelGGL(gauss_prep_kernel,
                       dim3((N_GAUSS + 255) / 256), dim3(256), 0, stream,
                       means, scales, rotations, opacities, semantics, params);

    hipLaunchKernelGGL(gauss_occ_main_kernel,
                       dim3(256 * N_SPLIT), dim3(512), 0, stream,
                       xyz, params, out);
}